// Round 16
// baseline (336.740 us; speedup 1.0000x reference)
//
#include <hip/hip_runtime.h>
#include <hip/hip_bf16.h>

#define VOCAB 50257
#define EMBED 128
#define BATCH 4096
#define CTX   8

#define BM 128
#define NXT 786            // 64-col strips
#define VPAD 50304
#define LDSP 136

#define CHUNKS 99          // 512-col chunks per band (98 full + tail)
#define NBAND 32           // 128-row bands

typedef __attribute__((ext_vector_type(8))) short bf16x8;
typedef __attribute__((ext_vector_type(4))) float f32x4;
typedef float f32x4u __attribute__((ext_vector_type(4), aligned(4)));

static __device__ __forceinline__ ushort f2bf(float f) {
  __hip_bfloat16 h = __float2bfloat16(f);
  return *reinterpret_cast<ushort*>(&h);
}

// ---------------- Kernel 1: embedding bag -> bf16 word_emb ----------------
__global__ __launch_bounds__(256) void embed_bag_kernel(
    const int* __restrict__ idx, const float* __restrict__ Wp,
    __hip_bfloat16* __restrict__ emb) {
  int wave = threadIdx.x >> 6;
  int lane = threadIdx.x & 63;
  int row  = blockIdx.x * 4 + wave;
  const int* ri = idx + row * CTX;
  int e0 = lane * 2;
  float s0 = 0.f, s1 = 0.f;
#pragma unroll
  for (int c = 0; c < CTX; ++c) {
    int w = ri[c];
    float2 wv = *reinterpret_cast<const float2*>(Wp + (size_t)w * EMBED + e0);
    s0 += wv.x; s1 += wv.y;
  }
  __hip_bfloat162 pv;
  pv.x = __float2bfloat16(s0);
  pv.y = __float2bfloat16(s1);
  *reinterpret_cast<__hip_bfloat162*>(emb + (size_t)row * EMBED + e0) = pv;
}

// ------- Kernel 1b: W_pred [128][50257]f32 -> Btf fragment-ordered bf16 -------
__global__ __launch_bounds__(256) void transpose_b_kernel(
    const float* __restrict__ Bm, ushort* __restrict__ Btf) {
  __shared__ ushort Bs[64 * LDSP];
  int x = blockIdx.x;
  int cbase = x * 64;
  int tid = threadIdx.x;
  bool edge = (cbase + 64 > VOCAB);
#pragma unroll
  for (int i = 0; i < 8; ++i) {
    int c  = tid + i * 256;
    int e  = c >> 4;
    int v4 = (c & 15) << 2;
    int col = cbase + v4;
    float4 b;
    if (!edge) {
      b = *reinterpret_cast<const float4*>(Bm + (size_t)e * VOCAB + col);
    } else {
      b.x = (col + 0 < VOCAB) ? Bm[(size_t)e * VOCAB + col + 0] : 0.f;
      b.y = (col + 1 < VOCAB) ? Bm[(size_t)e * VOCAB + col + 1] : 0.f;
      b.z = (col + 2 < VOCAB) ? Bm[(size_t)e * VOCAB + col + 2] : 0.f;
      b.w = (col + 3 < VOCAB) ? Bm[(size_t)e * VOCAB + col + 3] : 0.f;
    }
    Bs[(v4 + 0) * LDSP + e] = f2bf(b.x);
    Bs[(v4 + 1) * LDSP + e] = f2bf(b.y);
    Bs[(v4 + 2) * LDSP + e] = f2bf(b.z);
    Bs[(v4 + 3) * LDSP + e] = f2bf(b.w);
  }
  __syncthreads();
  int lane = tid & 63, wv = tid >> 6;
  int lr = lane & 15, lg = lane >> 4;
#pragma unroll
  for (int p = 0; p < 4; ++p) {
    int instr = p * 4 + wv;
    int kq = instr >> 2, n = instr & 3;
    int v  = n * 16 + lr;
    int e0 = kq * 32 + lg * 8;
    uint4 val = *reinterpret_cast<const uint4*>(&Bs[v * LDSP + e0]);
    *reinterpret_cast<uint4*>(Btf + (size_t)x * 8192 + instr * 512 + lane * 8) = val;
  }
}

// ------ Kernel 2: R15 structure + NONTEMPORAL 512B-run stores (H9 test) ------
// Identical to gemm14 (XCD-pinned chunks, band-major tickets, per-wave LDS
// C-tile, amp-1.0 single-writer monotone rows). Single change: C stores are
// nontemporal -> bypass the L2 write-allocate/evict path (hypothesized ~3TB/s
// cap). Runs are 512B contiguous per row per instruction, so only head/tail
// sectors (row phase 4 mod 32) can RMW at DRAM (predicted amp <=1.06), unlike
// R7's 16B scatter (amp 1.76).
__global__ __launch_bounds__(256, 2) void gemm15_kernel(
    const ushort* __restrict__ A,       // emb bf16 [4096][128]
    const ushort* __restrict__ Btf,     // [786][16][64][8] bf16 frag-ordered
    float* __restrict__ C,
    unsigned int* __restrict__ cnt) {   // 8 per-XCD counters
  __shared__ float Cs[4][64 * 68];      // 69632 B
  __shared__ unsigned int sT;

  int xcd  = blockIdx.x & 7;
  int nloc = (CHUNKS - xcd + 7) >> 3;   // 13 for xcd<3, else 12
  unsigned int ntick = (unsigned int)(NBAND * nloc);

  int tid  = threadIdx.x;
  int lane = tid & 63;
  int wv   = tid >> 6;
  int lr   = lane & 15;
  int lg   = lane >> 4;

  float* Csw = &Cs[wv][0];
  int wbase   = lane * 68;              // stage base (f32 units)
  int row_off = lane >> 5;              // readback: row parity
  int c4  = lane & 31;                  // readback: dword4 index in 128 cols
  int rni = c4 >> 2;                    // readback: source n-step
  int rlg = c4 & 3;                     // readback: source lg

  for (;;) {
    __syncthreads();
    if (tid == 0) sT = atomicAdd(&cnt[xcd], 1u);
    __syncthreads();
    unsigned int t = sT;
    if (t >= ntick) break;

    int band = (int)(t / nloc);
    int c    = (int)(t % nloc) * 8 + xcd;   // XCD-local chunk
    int R0   = band * 128 + wv * 32;

    // A fragments for this wave's 32 rows (L2-resident)
    const ushort* Ag = A + (size_t)R0 * EMBED;
    bf16x8 af[2][4];
#pragma unroll
    for (int m = 0; m < 2; ++m)
#pragma unroll
      for (int kq = 0; kq < 4; ++kq)
        af[m][kq] = *reinterpret_cast<const bf16x8*>(
            Ag + (m * 16 + lr) * EMBED + kq * 32 + lg * 8);

    int ngr = (c < CHUNKS - 1) ? 4 : 1;   // chunk 98 = tail group only
    for (int gg = 0; gg < ngr; ++gg) {
      int g = c * 4 + gg;                 // 128-col group id, 0..392
      const ushort* Bg0 = Btf + (size_t)(g * 2) * 8192 + lane * 8;
      if (g != 392) {
        // ---- compute 8 n-steps x 2 row-halves -> per-wave LDS ----
#pragma unroll
        for (int ni = 0; ni < 8; ++ni) {
          const ushort* Bp = Bg0 + (size_t)(ni >> 2) * 8192;
          int n = ni & 3;
          bf16x8 b[4];
#pragma unroll
          for (int kq = 0; kq < 4; ++kq)
            b[kq] = *reinterpret_cast<const bf16x8*>(Bp + (kq * 4 + n) * 512);
          f32x4 acc0 = {0.f, 0.f, 0.f, 0.f};
          f32x4 acc1 = {0.f, 0.f, 0.f, 0.f};
#pragma unroll
          for (int kq = 0; kq < 4; ++kq) {
            acc0 = __builtin_amdgcn_mfma_f32_16x16x32_bf16(b[kq], af[0][kq], acc0, 0, 0, 0);
            acc1 = __builtin_amdgcn_mfma_f32_16x16x32_bf16(b[kq], af[1][kq], acc1, 0, 0, 0);
          }
          *reinterpret_cast<f32x4*>(&Csw[wbase + ni * 8])     = acc0;
          *reinterpret_cast<f32x4*>(&Csw[wbase + ni * 8 + 4]) = acc1;
        }
        // ---- readback + 16 NT stores (2 rows x 512B contiguous each) ----
        f32x4 v[16];
#pragma unroll
        for (int p = 0; p < 16; ++p) {
          int rr   = p * 2 + row_off;                 // 0..31
          int srcl = rlg * 16 + (rr & 15);
          int off  = rni * 8 + (rr >> 4) * 4;
          v[p] = *reinterpret_cast<const f32x4*>(&Csw[srcl * 68 + off]);
        }
        int colbase = g * 128 + c4 * 4;
#pragma unroll
        for (int p = 0; p < 16; ++p)
          __builtin_nontemporal_store(
              __builtin_bit_cast(f32x4u, v[p]),
              reinterpret_cast<f32x4u*>(
                  C + (size_t)(R0 + p * 2 + row_off) * VOCAB + colbase));
      } else {
        // ---- tail group 392: cols 50176..50256 (81 valid) ----
#pragma unroll
        for (int ni = 0; ni < 8; ++ni) {
          const ushort* Bp = Bg0 + (size_t)(ni >> 2) * 8192;
          int n = ni & 3;
          bf16x8 b[4];
#pragma unroll
          for (int kq = 0; kq < 4; ++kq)
            b[kq] = *reinterpret_cast<const bf16x8*>(Bp + (kq * 4 + n) * 512);
          f32x4 acc0 = {0.f, 0.f, 0.f, 0.f};
          f32x4 acc1 = {0.f, 0.f, 0.f, 0.f};
#pragma unroll
          for (int kq = 0; kq < 4; ++kq) {
            acc0 = __builtin_amdgcn_mfma_f32_16x16x32_bf16(b[kq], af[0][kq], acc0, 0, 0, 0);
            acc1 = __builtin_amdgcn_mfma_f32_16x16x32_bf16(b[kq], af[1][kq], acc1, 0, 0, 0);
          }
          *reinterpret_cast<f32x4*>(&Csw[wbase + ni * 8])     = acc0;
          *reinterpret_cast<f32x4*>(&Csw[wbase + ni * 8 + 4]) = acc1;
        }
        int colbase = 392 * 128 + c4 * 4;   // 50176 + c4*4
#pragma unroll
        for (int p = 0; p < 16; ++p) {
          if (c4 < 21) {
            int rr   = p * 2 + row_off;
            int srcl = rlg * 16 + (rr & 15);
            int off  = rni * 8 + (rr >> 4) * 4;
            f32x4 v = *reinterpret_cast<const f32x4*>(&Csw[srcl * 68 + off]);
            float* cp = C + (size_t)(R0 + rr) * VOCAB + colbase;
            if (c4 < 20) {
              __builtin_nontemporal_store(__builtin_bit_cast(f32x4u, v),
                                          reinterpret_cast<f32x4u*>(cp));
            } else {
              __builtin_nontemporal_store(v[0], cp);   // col 50256
            }
          }
        }
      }
    }
  }
}

// ---------------- Fallback GEMM (R2 style) if ws too small ----------------
#define FLDSP 132
__global__ __launch_bounds__(256, 4) void gemm_kernel(
    const __hip_bfloat16* __restrict__ A,
    const float* __restrict__ Bm,
    float* __restrict__ C) {
  __shared__ char BsRaw[64 * FLDSP * 2];
  int bid = blockIdx.x;
  int k8  = bid & 7;
  int j   = bid >> 3;
  int t   = j >> 5;
  int y   = j & 31;
  int x   = k8 + t * 8;
  if (x >= NXT) return;

  int tid  = threadIdx.x;
  int lane = tid & 63;
  int wv   = tid >> 6;
  int lr   = lane & 15;
  int lg   = lane >> 4;
  int r0   = wv * 32;

  const ushort* Ag = reinterpret_cast<const ushort*>(A) + (size_t)(y * BM) * EMBED;
  uint4 a_raw[2][4];
#pragma unroll
  for (int m = 0; m < 2; ++m)
#pragma unroll
    for (int kq = 0; kq < 4; ++kq)
      a_raw[m][kq] = *reinterpret_cast<const uint4*>(
          Ag + (r0 + m * 16 + lr) * EMBED + kq * 32 + lg * 8);

  int cbase = x * 64;
  bool edge = (x == NXT - 1);
  float4 bb[8];
#pragma unroll
  for (int i = 0; i < 8; ++i) {
    int c  = tid + i * 256;
    int e  = c >> 4;
    int v4 = (c & 15) << 2;
    int col = cbase + v4;
    if (!edge) {
      bb[i] = *reinterpret_cast<const float4*>(Bm + (size_t)e * VOCAB + col);
    } else {
      bb[i].x = (col + 0 < VOCAB) ? Bm[(size_t)e * VOCAB + col + 0] : 0.f;
      bb[i].y = (col + 1 < VOCAB) ? Bm[(size_t)e * VOCAB + col + 1] : 0.f;
      bb[i].z = (col + 2 < VOCAB) ? Bm[(size_t)e * VOCAB + col + 2] : 0.f;
      bb[i].w = (col + 3 < VOCAB) ? Bm[(size_t)e * VOCAB + col + 3] : 0.f;
    }
  }
#pragma unroll
  for (int i = 0; i < 8; ++i) {
    int c  = tid + i * 256;
    int e  = c >> 4;
    int v4 = (c & 15) << 2;
    float vals[4] = {bb[i].x, bb[i].y, bb[i].z, bb[i].w};
#pragma unroll
    for (int jj = 0; jj < 4; ++jj) {
      int v   = v4 + jj;
      int off = v * (FLDSP * 2) + ((e * 2) ^ ((v & 28) << 2));
      *reinterpret_cast<ushort*>(BsRaw + off) = f2bf(vals[jj]);
    }
  }
  __syncthreads();

  f32x4 acc[2][4] = {};
#pragma unroll
  for (int kq = 0; kq < 4; ++kq) {
    int ebyte = (kq * 32 + lg * 8) * 2;
    bf16x8 bfr[4];
#pragma unroll
    for (int n = 0; n < 4; ++n) {
      int v   = n * 16 + lr;
      int off = v * (FLDSP * 2) + (ebyte ^ ((v & 28) << 2));
      bfr[n] = *reinterpret_cast<const bf16x8*>(BsRaw + off);
    }
#pragma unroll
    for (int m = 0; m < 2; ++m) {
      bf16x8 af = __builtin_bit_cast(bf16x8, a_raw[m][kq]);
#pragma unroll
      for (int n = 0; n < 4; ++n)
        acc[m][n] = __builtin_amdgcn_mfma_f32_16x16x32_bf16(af, bfr[n], acc[m][n], 0, 0, 0);
    }
  }

  size_t crow0 = (size_t)y * BM + r0;
#pragma unroll
  for (int m = 0; m < 2; ++m) {
#pragma unroll
    for (int n = 0; n < 4; ++n) {
      int colc = cbase + n * 16 + lr;
      if (colc < VOCAB) {
        float* cp = C + (crow0 + m * 16 + lg * 4) * (size_t)VOCAB + colc;
#pragma unroll
        for (int q = 0; q < 4; ++q)
          cp[(size_t)q * VOCAB] = acc[m][n][q];
      }
    }
  }
}

extern "C" void kernel_launch(void* const* d_in, const int* in_sizes, int n_in,
                              void* d_out, int out_size, void* d_ws, size_t ws_size,
                              hipStream_t stream) {
  const int*   idx    = (const int*)d_in[0];
  const float* W_proj = (const float*)d_in[1];
  const float* W_pred = (const float*)d_in[2];
  float*       out    = (float*)d_out;

  __hip_bfloat16* emb = (__hip_bfloat16*)d_ws;                 // [0, 1MB)
  ushort* Btf = (ushort*)((char*)d_ws + (size_t)1048576);      // [1MB, ~13.9MB)
  unsigned int* cnt = (unsigned int*)((char*)d_ws + (size_t)14680064);  // @14MB
  const size_t needed = (size_t)14680064 + 64;

  embed_bag_kernel<<<BATCH / 4, 256, 0, stream>>>(idx, W_proj, emb);

  if (ws_size >= needed) {
    transpose_b_kernel<<<NXT, 256, 0, stream>>>(W_pred, Btf);
    hipMemsetAsync(cnt, 0, 8 * sizeof(unsigned int), stream);
    gemm15_kernel<<<512, 256, 0, stream>>>((const ushort*)emb, Btf, out, cnt);
  } else {
    int strips = (NXT + 7) / 8;
    int grid = 8 * strips * 32;
    gemm_kernel<<<grid, 256, 0, stream>>>(emb, W_pred, out);
  }
}

// Round 17
// 316.967 us; speedup vs baseline: 1.0624x; 1.0624x over previous
//
#include <hip/hip_runtime.h>
#include <hip/hip_bf16.h>

#define VOCAB 50257
#define EMBED 128
#define BATCH 4096
#define CTX   8

#define BM 128
#define NXT 786            // 64-col strips
#define VPAD 50304
#define LDSP 136

#define CHUNKS 99          // 512-col chunks per band (98 full + tail)
#define NBAND 32           // 128-row bands

typedef __attribute__((ext_vector_type(8))) short bf16x8;
typedef __attribute__((ext_vector_type(4))) float f32x4;
typedef float f32x4u __attribute__((ext_vector_type(4), aligned(4)));

static __device__ __forceinline__ ushort f2bf(float f) {
  __hip_bfloat16 h = __float2bfloat16(f);
  return *reinterpret_cast<ushort*>(&h);
}

// ---- Fused prologue: embed (blocks 0..1023) | transpose (1024..1809) | cnt=0 (1810) ----
// embed and transpose are data-independent; fusing removes one launch gap and
// the hipMemsetAsync dispatch (counter zeroing rides along in block 1810).
__global__ __launch_bounds__(256) void prep_kernel(
    const int* __restrict__ idx, const float* __restrict__ Wp,
    const float* __restrict__ Bm,
    __hip_bfloat16* __restrict__ emb, ushort* __restrict__ Btf,
    unsigned int* __restrict__ cnt) {
  __shared__ ushort Bs[64 * LDSP];
  int bid = blockIdx.x;
  int tid = threadIdx.x;

  if (bid < 1024) {
    // ---- embedding bag: 4 rows per block, one wave each ----
    int wave = tid >> 6;
    int lane = tid & 63;
    int row  = bid * 4 + wave;
    const int* ri = idx + row * CTX;
    int e0 = lane * 2;
    float s0 = 0.f, s1 = 0.f;
#pragma unroll
    for (int c = 0; c < CTX; ++c) {
      int w = ri[c];
      float2 wv = *reinterpret_cast<const float2*>(Wp + (size_t)w * EMBED + e0);
      s0 += wv.x; s1 += wv.y;
    }
    __hip_bfloat162 pv;
    pv.x = __float2bfloat16(s0);
    pv.y = __float2bfloat16(s1);
    *reinterpret_cast<__hip_bfloat162*>(emb + (size_t)row * EMBED + e0) = pv;
  } else if (bid < 1024 + NXT) {
    // ---- W_pred [128][50257]f32 -> Btf fragment-ordered bf16 ----
    int x = bid - 1024;
    int cbase = x * 64;
    bool edge = (cbase + 64 > VOCAB);
#pragma unroll
    for (int i = 0; i < 8; ++i) {
      int c  = tid + i * 256;
      int e  = c >> 4;
      int v4 = (c & 15) << 2;
      int col = cbase + v4;
      float4 b;
      if (!edge) {
        b = *reinterpret_cast<const float4*>(Bm + (size_t)e * VOCAB + col);
      } else {
        b.x = (col + 0 < VOCAB) ? Bm[(size_t)e * VOCAB + col + 0] : 0.f;
        b.y = (col + 1 < VOCAB) ? Bm[(size_t)e * VOCAB + col + 1] : 0.f;
        b.z = (col + 2 < VOCAB) ? Bm[(size_t)e * VOCAB + col + 2] : 0.f;
        b.w = (col + 3 < VOCAB) ? Bm[(size_t)e * VOCAB + col + 3] : 0.f;
      }
      Bs[(v4 + 0) * LDSP + e] = f2bf(b.x);
      Bs[(v4 + 1) * LDSP + e] = f2bf(b.y);
      Bs[(v4 + 2) * LDSP + e] = f2bf(b.z);
      Bs[(v4 + 3) * LDSP + e] = f2bf(b.w);
    }
    __syncthreads();
    int lane = tid & 63, wv = tid >> 6;
    int lr = lane & 15, lg = lane >> 4;
#pragma unroll
    for (int p = 0; p < 4; ++p) {
      int instr = p * 4 + wv;
      int kq = instr >> 2, n = instr & 3;
      int v  = n * 16 + lr;
      int e0 = kq * 32 + lg * 8;
      uint4 val = *reinterpret_cast<const uint4*>(&Bs[v * LDSP + e0]);
      *reinterpret_cast<uint4*>(Btf + (size_t)x * 8192 + instr * 512 + lane * 8) = val;
    }
  } else {
    if (tid < 8) cnt[tid] = 0u;
  }
}

// ------ GEMM: XCD-pinned chunks, band-major tickets, per-wave LDS C-tile ------
// (R15 champion config, regular write-back stores.) 512 blocks (2/CU).
// Block's XCD = bid&7; each XCD processes only chunks c ≡ xcd (mod 8) via its
// own atomic counter, sweeping bands in the same order -> its 1.6MB Btf slice
// is L2-resident across all 32 band sweeps. Band-dense eviction window
// (~5 bands / 133MB < L3). Per 128-col group: 8 n-steps {4 B-frag loads,
// 8 MFMA swapped, 2 ds_write_b128}, then 16 ds_read_b128 + 16 stores of
// 2 rows x 512B contiguous single-writer monotone rows (amp 1.0).
__global__ __launch_bounds__(256, 2) void gemm14_kernel(
    const ushort* __restrict__ A,       // emb bf16 [4096][128]
    const ushort* __restrict__ Btf,     // [786][16][64][8] bf16 frag-ordered
    float* __restrict__ C,
    unsigned int* __restrict__ cnt) {   // 8 per-XCD counters
  __shared__ float Cs[4][64 * 68];      // 69632 B
  __shared__ unsigned int sT;

  int xcd  = blockIdx.x & 7;
  int nloc = (CHUNKS - xcd + 7) >> 3;   // 13 for xcd<3, else 12
  unsigned int ntick = (unsigned int)(NBAND * nloc);

  int tid  = threadIdx.x;
  int lane = tid & 63;
  int wv   = tid >> 6;
  int lr   = lane & 15;
  int lg   = lane >> 4;

  float* Csw = &Cs[wv][0];
  int wbase   = lane * 68;              // stage base (f32 units)
  int row_off = lane >> 5;              // readback: row parity
  int c4  = lane & 31;                  // readback: dword4 index in 128 cols
  int rni = c4 >> 2;                    // readback: source n-step
  int rlg = c4 & 3;                     // readback: source lg

  for (;;) {
    __syncthreads();
    if (tid == 0) sT = atomicAdd(&cnt[xcd], 1u);
    __syncthreads();
    unsigned int t = sT;
    if (t >= ntick) break;

    int band = (int)(t / nloc);
    int c    = (int)(t % nloc) * 8 + xcd;   // XCD-local chunk
    int R0   = band * 128 + wv * 32;

    // A fragments for this wave's 32 rows (L2-resident)
    const ushort* Ag = A + (size_t)R0 * EMBED;
    bf16x8 af[2][4];
#pragma unroll
    for (int m = 0; m < 2; ++m)
#pragma unroll
      for (int kq = 0; kq < 4; ++kq)
        af[m][kq] = *reinterpret_cast<const bf16x8*>(
            Ag + (m * 16 + lr) * EMBED + kq * 32 + lg * 8);

    int ngr = (c < CHUNKS - 1) ? 4 : 1;   // chunk 98 = tail group only
    for (int gg = 0; gg < ngr; ++gg) {
      int g = c * 4 + gg;                 // 128-col group id, 0..392
      const ushort* Bg0 = Btf + (size_t)(g * 2) * 8192 + lane * 8;
      if (g != 392) {
        // ---- compute 8 n-steps x 2 row-halves -> per-wave LDS ----
#pragma unroll
        for (int ni = 0; ni < 8; ++ni) {
          const ushort* Bp = Bg0 + (size_t)(ni >> 2) * 8192;
          int n = ni & 3;
          bf16x8 b[4];
#pragma unroll
          for (int kq = 0; kq < 4; ++kq)
            b[kq] = *reinterpret_cast<const bf16x8*>(Bp + (kq * 4 + n) * 512);
          f32x4 acc0 = {0.f, 0.f, 0.f, 0.f};
          f32x4 acc1 = {0.f, 0.f, 0.f, 0.f};
#pragma unroll
          for (int kq = 0; kq < 4; ++kq) {
            acc0 = __builtin_amdgcn_mfma_f32_16x16x32_bf16(b[kq], af[0][kq], acc0, 0, 0, 0);
            acc1 = __builtin_amdgcn_mfma_f32_16x16x32_bf16(b[kq], af[1][kq], acc1, 0, 0, 0);
          }
          *reinterpret_cast<f32x4*>(&Csw[wbase + ni * 8])     = acc0;
          *reinterpret_cast<f32x4*>(&Csw[wbase + ni * 8 + 4]) = acc1;
        }
        // ---- readback + 16 stores (2 rows x 512B contiguous each) ----
        f32x4 v[16];
#pragma unroll
        for (int p = 0; p < 16; ++p) {
          int rr   = p * 2 + row_off;                 // 0..31
          int srcl = rlg * 16 + (rr & 15);
          int off  = rni * 8 + (rr >> 4) * 4;
          v[p] = *reinterpret_cast<const f32x4*>(&Csw[srcl * 68 + off]);
        }
        int colbase = g * 128 + c4 * 4;
#pragma unroll
        for (int p = 0; p < 16; ++p)
          *reinterpret_cast<f32x4u*>(
              C + (size_t)(R0 + p * 2 + row_off) * VOCAB + colbase) =
              __builtin_bit_cast(f32x4u, v[p]);
      } else {
        // ---- tail group 392: cols 50176..50256 (81 valid) ----
#pragma unroll
        for (int ni = 0; ni < 8; ++ni) {
          const ushort* Bp = Bg0 + (size_t)(ni >> 2) * 8192;
          int n = ni & 3;
          bf16x8 b[4];
#pragma unroll
          for (int kq = 0; kq < 4; ++kq)
            b[kq] = *reinterpret_cast<const bf16x8*>(Bp + (kq * 4 + n) * 512);
          f32x4 acc0 = {0.f, 0.f, 0.f, 0.f};
          f32x4 acc1 = {0.f, 0.f, 0.f, 0.f};
#pragma unroll
          for (int kq = 0; kq < 4; ++kq) {
            acc0 = __builtin_amdgcn_mfma_f32_16x16x32_bf16(b[kq], af[0][kq], acc0, 0, 0, 0);
            acc1 = __builtin_amdgcn_mfma_f32_16x16x32_bf16(b[kq], af[1][kq], acc1, 0, 0, 0);
          }
          *reinterpret_cast<f32x4*>(&Csw[wbase + ni * 8])     = acc0;
          *reinterpret_cast<f32x4*>(&Csw[wbase + ni * 8 + 4]) = acc1;
        }
        int colbase = 392 * 128 + c4 * 4;   // 50176 + c4*4
#pragma unroll
        for (int p = 0; p < 16; ++p) {
          if (c4 < 21) {
            int rr   = p * 2 + row_off;
            int srcl = rlg * 16 + (rr & 15);
            int off  = rni * 8 + (rr >> 4) * 4;
            f32x4 v = *reinterpret_cast<const f32x4*>(&Csw[srcl * 68 + off]);
            float* cp = C + (size_t)(R0 + rr) * VOCAB + colbase;
            if (c4 < 20) {
              *reinterpret_cast<f32x4u*>(cp) = __builtin_bit_cast(f32x4u, v);
            } else {
              cp[0] = v[0];                 // col 50256
            }
          }
        }
      }
    }
  }
}

// ---------------- Fallback path (ws too small) ----------------
__global__ __launch_bounds__(256) void embed_bag_kernel(
    const int* __restrict__ idx, const float* __restrict__ Wp,
    __hip_bfloat16* __restrict__ emb) {
  int wave = threadIdx.x >> 6;
  int lane = threadIdx.x & 63;
  int row  = blockIdx.x * 4 + wave;
  const int* ri = idx + row * CTX;
  int e0 = lane * 2;
  float s0 = 0.f, s1 = 0.f;
#pragma unroll
  for (int c = 0; c < CTX; ++c) {
    int w = ri[c];
    float2 wv = *reinterpret_cast<const float2*>(Wp + (size_t)w * EMBED + e0);
    s0 += wv.x; s1 += wv.y;
  }
  __hip_bfloat162 pv;
  pv.x = __float2bfloat16(s0);
  pv.y = __float2bfloat16(s1);
  *reinterpret_cast<__hip_bfloat162*>(emb + (size_t)row * EMBED + e0) = pv;
}

#define FLDSP 132
__global__ __launch_bounds__(256, 4) void gemm_kernel(
    const __hip_bfloat16* __restrict__ A,
    const float* __restrict__ Bm,
    float* __restrict__ C) {
  __shared__ char BsRaw[64 * FLDSP * 2];
  int bid = blockIdx.x;
  int k8  = bid & 7;
  int j   = bid >> 3;
  int t   = j >> 5;
  int y   = j & 31;
  int x   = k8 + t * 8;
  if (x >= NXT) return;

  int tid  = threadIdx.x;
  int lane = tid & 63;
  int wv   = tid >> 6;
  int lr   = lane & 15;
  int lg   = lane >> 4;
  int r0   = wv * 32;

  const ushort* Ag = reinterpret_cast<const ushort*>(A) + (size_t)(y * BM) * EMBED;
  uint4 a_raw[2][4];
#pragma unroll
  for (int m = 0; m < 2; ++m)
#pragma unroll
    for (int kq = 0; kq < 4; ++kq)
      a_raw[m][kq] = *reinterpret_cast<const uint4*>(
          Ag + (r0 + m * 16 + lr) * EMBED + kq * 32 + lg * 8);

  int cbase = x * 64;
  bool edge = (x == NXT - 1);
  float4 bb[8];
#pragma unroll
  for (int i = 0; i < 8; ++i) {
    int c  = tid + i * 256;
    int e  = c >> 4;
    int v4 = (c & 15) << 2;
    int col = cbase + v4;
    if (!edge) {
      bb[i] = *reinterpret_cast<const float4*>(Bm + (size_t)e * VOCAB + col);
    } else {
      bb[i].x = (col + 0 < VOCAB) ? Bm[(size_t)e * VOCAB + col + 0] : 0.f;
      bb[i].y = (col + 1 < VOCAB) ? Bm[(size_t)e * VOCAB + col + 1] : 0.f;
      bb[i].z = (col + 2 < VOCAB) ? Bm[(size_t)e * VOCAB + col + 2] : 0.f;
      bb[i].w = (col + 3 < VOCAB) ? Bm[(size_t)e * VOCAB + col + 3] : 0.f;
    }
  }
#pragma unroll
  for (int i = 0; i < 8; ++i) {
    int c  = tid + i * 256;
    int e  = c >> 4;
    int v4 = (c & 15) << 2;
    float vals[4] = {bb[i].x, bb[i].y, bb[i].z, bb[i].w};
#pragma unroll
    for (int jj = 0; jj < 4; ++jj) {
      int v   = v4 + jj;
      int off = v * (FLDSP * 2) + ((e * 2) ^ ((v & 28) << 2));
      *reinterpret_cast<ushort*>(BsRaw + off) = f2bf(vals[jj]);
    }
  }
  __syncthreads();

  f32x4 acc[2][4] = {};
#pragma unroll
  for (int kq = 0; kq < 4; ++kq) {
    int ebyte = (kq * 32 + lg * 8) * 2;
    bf16x8 bfr[4];
#pragma unroll
    for (int n = 0; n < 4; ++n) {
      int v   = n * 16 + lr;
      int off = v * (FLDSP * 2) + (ebyte ^ ((v & 28) << 2));
      bfr[n] = *reinterpret_cast<const bf16x8*>(BsRaw + off);
    }
#pragma unroll
    for (int m = 0; m < 2; ++m) {
      bf16x8 af = __builtin_bit_cast(bf16x8, a_raw[m][kq]);
#pragma unroll
      for (int n = 0; n < 4; ++n)
        acc[m][n] = __builtin_amdgcn_mfma_f32_16x16x32_bf16(af, bfr[n], acc[m][n], 0, 0, 0);
    }
  }

  size_t crow0 = (size_t)y * BM + r0;
#pragma unroll
  for (int m = 0; m < 2; ++m) {
#pragma unroll
    for (int n = 0; n < 4; ++n) {
      int colc = cbase + n * 16 + lr;
      if (colc < VOCAB) {
        float* cp = C + (crow0 + m * 16 + lg * 4) * (size_t)VOCAB + colc;
#pragma unroll
        for (int q = 0; q < 4; ++q)
          cp[(size_t)q * VOCAB] = acc[m][n][q];
      }
    }
  }
}

extern "C" void kernel_launch(void* const* d_in, const int* in_sizes, int n_in,
                              void* d_out, int out_size, void* d_ws, size_t ws_size,
                              hipStream_t stream) {
  const int*   idx    = (const int*)d_in[0];
  const float* W_proj = (const float*)d_in[1];
  const float* W_pred = (const float*)d_in[2];
  float*       out    = (float*)d_out;

  __hip_bfloat16* emb = (__hip_bfloat16*)d_ws;                 // [0, 1MB)
  ushort* Btf = (ushort*)((char*)d_ws + (size_t)1048576);      // [1MB, ~13.9MB)
  unsigned int* cnt = (unsigned int*)((char*)d_ws + (size_t)14680064);  // @14MB
  const size_t needed = (size_t)14680064 + 64;

  if (ws_size >= needed) {
    prep_kernel<<<1024 + NXT + 1, 256, 0, stream>>>(idx, W_proj, W_pred, emb, Btf, cnt);
    gemm14_kernel<<<512, 256, 0, stream>>>((const ushort*)emb, Btf, out, cnt);
  } else {
    embed_bag_kernel<<<BATCH / 4, 256, 0, stream>>>(idx, W_proj, emb);
    int strips = (NXT + 7) / 8;
    int grid = 8 * strips * 32;
    gemm_kernel<<<grid, 256, 0, stream>>>(emb, W_pred, out);
  }
}